// Round 6
// baseline (261.839 us; speedup 1.0000x reference)
//
#include <hip/hip_runtime.h>
#include <hip/hip_bf16.h>

// Problem constants: G=64, C=32, L=128, D=64, H=128, NCLS=10
#define NSEQ 2048   // G*C
#define LSEQ 128
#define DIN  64
#define HID  128
#define NCLS 10
#define SEQB 4      // sequences per block (2 blocks/CU -> independent barrier domains)
#define XPAD 80     // padded x row stride in shorts (x rows: 64 values)
#define HPAD 136    // padded h row stride in shorts (h rows: 128 values) — R0-proven
#define CHK  16     // timesteps staged per chunk

typedef __attribute__((ext_vector_type(8))) short bfrag8;   // 8 bf16 (MFMA A/B frag)
typedef __attribute__((ext_vector_type(4))) float facc4;    // MFMA C/D frag

__device__ __forceinline__ short f2bf(float f) {
    union { __hip_bfloat16 b; short s; } u;
    u.b = __float2bfloat16(f);   // RNE
    return u.s;
}

__device__ __forceinline__ bfrag8 load_bf16_frag(const float* __restrict__ p) {
    bfrag8 r;
#pragma unroll
    for (int j = 0; j < 8; ++j) r[j] = f2bf(p[j]);
    return r;
}

__device__ __forceinline__ float fast_sigmoid(float x) {
    float e = __builtin_amdgcn_exp2f(-1.4426950408889634f * x);
    return __builtin_amdgcn_rcpf(1.0f + e);
}
__device__ __forceinline__ float fast_tanh(float x) {
    float e = __builtin_amdgcn_exp2f(2.8853900817779268f * x);
    return 1.0f - 2.0f * __builtin_amdgcn_rcpf(1.0f + e);
}

// One block = 4 sequences, 8 waves; grid 512 = 2 blocks/CU with INDEPENDENT
// barriers (anti-phase overlap: one block's MFMAs fill the other's serial
// chain stalls).  Dup-row trick: A-frags read row (ln&3) for both h and x, so
// all 16 MFMA M-rows duplicate seqs 0-3 and every lane's C-frag element i is
// the gate pre-activation of seq i at col khid (C/D row = qd*4+i, seq = row&3
// = i) — NO cross-lane redistribute is needed (2 selects pick element qd),
// and the cell is 1 unit/lane.
// R5 bugfix: hbuf row stride was XPAD=80 (<128) -> h rows overlapped and
// spilled into xs. hbuf now has its own HPAD=136 stride (R0-proven layout).
__global__ __launch_bounds__(512) void lstm_fused(
    const float* __restrict__ x,      // [2048][128][64] f32
    const float* __restrict__ Wih,    // [512][64] f32
    const float* __restrict__ Whh,    // [512][128] f32
    const float* __restrict__ bih,    // [512] f32
    const float* __restrict__ bhh,    // [512] f32
    float* __restrict__ rep)          // [2048][128] f32 (d_ws)
{
    __shared__ __align__(16) __hip_bfloat16 hbuf[2][SEQB][HPAD];       // 2176 B
    __shared__ __align__(16) __hip_bfloat16 xs[2][CHK][SEQB][XPAD];    // 20480 B

    const int tid  = threadIdx.x;
    const int w    = tid >> 6;
    const int lane = tid & 63;
    const int ln   = lane & 15;
    const int qd   = lane >> 4;
    const int s0   = blockIdx.x * SEQB;
    const int khid = w * 16 + ln;

    // ---- weight B-fragments: f32 -> bf16 registers (reused all 128 steps) ----
    bfrag8 whh[4][4];
    bfrag8 wih[4][2];
    facc4  biasf[4];    // bias as persistent MFMA C-input
#pragma unroll
    for (int g = 0; g < 4; ++g) {
        const int col = g * HID + khid;
        const float b = bih[col] + bhh[col];
        biasf[g] = (facc4){b, b, b, b};
#pragma unroll
        for (int k0 = 0; k0 < 4; ++k0)
            whh[g][k0] = load_bf16_frag(Whh + col * HID + k0 * 32 + qd * 8);
#pragma unroll
        for (int k0 = 0; k0 < 2; ++k0)
            wih[g][k0] = load_bf16_frag(Wih + col * DIN + k0 * 32 + qd * 8);
    }

    // zero both h buffers (h(-1) = 0)
    {
        unsigned int* p = (unsigned int*)&hbuf[0][0][0];
        for (int i = tid; i < 2 * SEQB * HPAD / 2; i += 512) p[i] = 0u;
    }

    // x staging: waves 0-3 stage sequence s0+w; lane covers 16 consecutive f32
    // of step (lane>>2) in the chunk.
    const float* xsrc = x + (size_t)(s0 + (w & 3)) * (LSEQ * DIN) + lane * 16;
    const int stt = lane >> 2;
    const int sdd = (lane & 3) * 16;

    if (w < SEQB) {   // stage chunk 0
        float4 a0 = ((const float4*)xsrc)[0];
        float4 a1 = ((const float4*)xsrc)[1];
        float4 a2 = ((const float4*)xsrc)[2];
        float4 a3 = ((const float4*)xsrc)[3];
        bfrag8 o0, o1;
#pragma unroll
        for (int j = 0; j < 4; ++j) { o0[j] = f2bf(((float*)&a0)[j]); o0[4+j] = f2bf(((float*)&a1)[j]); }
#pragma unroll
        for (int j = 0; j < 4; ++j) { o1[j] = f2bf(((float*)&a2)[j]); o1[4+j] = f2bf(((float*)&a3)[j]); }
        *(bfrag8*)&xs[0][stt][w][sdd]     = o0;
        *(bfrag8*)&xs[0][stt][w][sdd + 8] = o1;
    }

    float cst  = 0.f;
    float hsum = 0.f;

    __syncthreads();

    // prologue: acc for t=0 = bias + x(0) @ Wih^T  (dup rows ln&3)
    facc4 accA[4], accB[4];
    {
        bfrag8 x0 = *(const bfrag8*)(&xs[0][0][ln & 3][qd * 8]);
        bfrag8 x1 = *(const bfrag8*)(&xs[0][0][ln & 3][32 + qd * 8]);
#pragma unroll
        for (int g = 0; g < 4; ++g) {
            accA[g] = __builtin_amdgcn_mfma_f32_16x16x32_bf16(x0, wih[g][0], biasf[g], 0, 0, 0);
            accA[g] = __builtin_amdgcn_mfma_f32_16x16x32_bf16(x1, wih[g][1], accA[g], 0, 0, 0);
        }
    }

    int cur = 0;

#define STEP(ACCIN, ACCOUT, CT)                                                          \
    {                                                                                    \
        const int ct = (CT);                                                             \
        /* h A-frags, dup rows ln&3 (post-barrier critical path) */                      \
        bfrag8 hf[4];                                                                    \
        _Pragma("unroll")                                                                \
        for (int k0 = 0; k0 < 4; ++k0)                                                   \
            hf[k0] = *(const bfrag8*)(&hbuf[cur][ln & 3][k0 * 32 + qd * 8]);             \
        /* x A-frags for t+1 (stable chunk buffer; ct==15 -> next chunk's buffer) */     \
        const int nbuf = (ct < CHK - 1) ? buf : (buf ^ 1);                               \
        const int nct  = (ct + 1) & (CHK - 1);                                           \
        bfrag8 xf0 = *(const bfrag8*)(&xs[nbuf][nct][ln & 3][qd * 8]);                   \
        bfrag8 xf1 = *(const bfrag8*)(&xs[nbuf][nct][ln & 3][32 + qd * 8]);              \
        /* h-part MFMAs into carried acc (which already holds bias + x(t)) */            \
        _Pragma("unroll")                                                                \
        for (int g = 0; g < 4; ++g)                                                      \
            _Pragma("unroll")                                                            \
            for (int k0 = 0; k0 < 4; ++k0)                                               \
                ACCIN[g] = __builtin_amdgcn_mfma_f32_16x16x32_bf16(hf[k0], whh[g][k0], ACCIN[g], 0, 0, 0); \
        /* every lane holds all 4 seqs' gates: element i = seq i. Pick seq=qd. */        \
        float u[4];                                                                      \
        _Pragma("unroll")                                                                \
        for (int g = 0; g < 4; ++g) {                                                    \
            float a01 = (qd & 1) ? ACCIN[g][1] : ACCIN[g][0];                            \
            float a23 = (qd & 1) ? ACCIN[g][3] : ACCIN[g][2];                            \
            u[g] = (qd & 2) ? a23 : a01;                                                 \
        }                                                                                \
        /* next step's x-part: fills MFMA pipe during cell phase (C = biasf) */          \
        _Pragma("unroll")                                                                \
        for (int g = 0; g < 4; ++g) {                                                    \
            ACCOUT[g] = __builtin_amdgcn_mfma_f32_16x16x32_bf16(xf0, wih[g][0], biasf[g], 0, 0, 0); \
            ACCOUT[g] = __builtin_amdgcn_mfma_f32_16x16x32_bf16(xf1, wih[g][1], ACCOUT[g], 0, 0, 0); \
        }                                                                                \
        if (ct == 0 && more && w < SEQB) {      /* issue next chunk's global loads */    \
            const float* p = xsrc + (chunk + 1) * (CHK * DIN);                           \
            l0 = ((const float4*)p)[0];                                                  \
            l1 = ((const float4*)p)[1];                                                  \
            l2 = ((const float4*)p)[2];                                                  \
            l3 = ((const float4*)p)[3];                                                  \
        }                                                                                \
        if (ct == 12 && more && w < SEQB) {     /* convert + write next chunk to LDS */  \
            bfrag8 o0, o1;                                                               \
            _Pragma("unroll")                                                            \
            for (int j = 0; j < 4; ++j) { o0[j] = f2bf(((float*)&l0)[j]); o0[4+j] = f2bf(((float*)&l1)[j]); } \
            _Pragma("unroll")                                                            \
            for (int j = 0; j < 4; ++j) { o1[j] = f2bf(((float*)&l2)[j]); o1[4+j] = f2bf(((float*)&l3)[j]); } \
            *(bfrag8*)&xs[buf ^ 1][stt][w][sdd]     = o0;                                \
            *(bfrag8*)&xs[buf ^ 1][stt][w][sdd + 8] = o1;                                \
        }                                                                                \
        /* LSTM cell: ONE (seq=qd, hid=khid) unit per lane */                            \
        {                                                                                \
            float iv = fast_sigmoid(u[0]);                                               \
            float fv = fast_sigmoid(u[1]);                                               \
            float gv = fast_tanh(u[2]);                                                  \
            float ov = fast_sigmoid(u[3]);                                               \
            float c  = fv * cst + iv * gv;                                               \
            cst      = c;                                                                \
            float hv = ov * fast_tanh(c);                                                \
            hsum    += hv;                                                               \
            ((short*)&hbuf[cur ^ 1][qd][0])[khid] = f2bf(hv);                            \
        }                                                                                \
        __syncthreads();                                                                 \
        cur ^= 1;                                                                        \
    }

    for (int chunk = 0; chunk < LSEQ / CHK; ++chunk) {
        const int buf = chunk & 1;
        const bool more = chunk < (LSEQ / CHK - 1);
        float4 l0, l1, l2, l3;
#pragma unroll 1
        for (int ct2 = 0; ct2 < CHK / 2; ++ct2) {
            STEP(accA, accB, 2 * ct2);
            STEP(accB, accA, 2 * ct2 + 1);
        }
    }
#undef STEP

    // rep[b][k] = sum_t h_t[b][k] — lane owns (seq=qd, col=khid)
    rep[(size_t)(s0 + qd) * HID + khid] = hsum;
}

// Epilogue: graph mean over C=32, classifier [10,128], log-softmax -> f32 out[64][10]
__global__ __launch_bounds__(128) void cls_kernel(
    const float* __restrict__ rep,    // [2048][128]
    const float* __restrict__ Wcls,   // [10][128]
    const float* __restrict__ bcls,   // [10]
    float* __restrict__ out)          // [64][10]
{
    __shared__ float m_s[HID];
    __shared__ float logits_s[NCLS];
    const int g = blockIdx.x;
    const int h = threadIdx.x;

    float s = 0.f;
#pragma unroll 4
    for (int c = 0; c < 32; ++c)
        s += rep[((size_t)g * 32 + c) * HID + h];
    m_s[h] = s * (1.0f / 32.0f);
    __syncthreads();

    if (h < NCLS) {
        float acc = bcls[h];
        for (int k = 0; k < HID; ++k)
            acc += m_s[k] * Wcls[h * HID + k];
        logits_s[h] = acc;
    }
    __syncthreads();

    if (h < NCLS) {
        float mx = logits_s[0];
#pragma unroll
        for (int j = 1; j < NCLS; ++j) mx = fmaxf(mx, logits_s[j]);
        float se = 0.f;
#pragma unroll
        for (int j = 0; j < NCLS; ++j)
            se += __builtin_amdgcn_exp2f((logits_s[j] - mx) * 1.4426950408889634f);
        float lse = mx + 0.6931471805599453f * __builtin_amdgcn_logf(se);
        out[g * NCLS + h] = logits_s[h] - lse;
    }
}

extern "C" void kernel_launch(void* const* d_in, const int* in_sizes, int n_in,
                              void* d_out, int out_size, void* d_ws, size_t ws_size,
                              hipStream_t stream) {
    const float* x    = (const float*)d_in[0];
    const float* Wih  = (const float*)d_in[1];
    const float* Whh  = (const float*)d_in[2];
    const float* bih  = (const float*)d_in[3];
    const float* bhh  = (const float*)d_in[4];
    const float* Wcls = (const float*)d_in[5];
    const float* bcls = (const float*)d_in[6];

    float* rep = (float*)d_ws;   // 2048*128 fp32 = 1 MB scratch

    lstm_fused<<<NSEQ / SEQB, 512, 0, stream>>>(x, Wih, Whh, bih, bhh, rep);
    cls_kernel<<<64, 128, 0, stream>>>(rep, Wcls, bcls, (float*)d_out);
}

// Round 7
// 191.097 us; speedup vs baseline: 1.3702x; 1.3702x over previous
//
#include <hip/hip_runtime.h>
#include <hip/hip_bf16.h>

// Problem constants: G=64, C=32, L=128, D=64, H=128, NCLS=10
#define NSEQ 2048   // G*C
#define LSEQ 128
#define DIN  64
#define HID  128
#define NCLS 10
#define XPAD 72     // padded x row (shorts)
#define HPAD 136    // padded h row (shorts)
#define CHK  16     // timesteps staged per chunk

typedef __attribute__((ext_vector_type(8))) short bfrag8;   // 8 bf16 (MFMA A/B frag)
typedef __attribute__((ext_vector_type(4))) float facc4;    // MFMA C/D frag

__device__ __forceinline__ short f2bf(float f) {
    union { __hip_bfloat16 b; short s; } u;
    u.b = __float2bfloat16(f);   // RNE
    return u.s;
}

__device__ __forceinline__ bfrag8 load_bf16_frag(const float* __restrict__ p) {
    bfrag8 r;
#pragma unroll
    for (int j = 0; j < 8; ++j) r[j] = f2bf(p[j]);
    return r;
}

__device__ __forceinline__ float fast_sigmoid(float x) {
    float e = __builtin_amdgcn_exp2f(-1.4426950408889634f * x);
    return __builtin_amdgcn_rcpf(1.0f + e);
}
__device__ __forceinline__ float fast_tanh(float x) {
    float e = __builtin_amdgcn_exp2f(2.8853900817779268f * x);
    return 1.0f - 2.0f * __builtin_amdgcn_rcpf(1.0f + e);
}

// One block = 8 sequences, 8 waves (R0 frame) with the 2x ROW-DUP map:
// MFMA M-row r carries seq r>>1 (A-frags read LDS row ln>>1), so the C-frag
// of lane (ln,qd) holds gate preacts for seq 2qd (elements 0,1 - dups) and
// seq 2qd+1 (elements 2,3) at col khid — the cross-lane permlane
// redistribute of R0 is eliminated ENTIRELY (the chain element R6 measured
// at several hundred cycles). Everything else is the proven R0 dataflow:
// cross-step x-prefetch into the carried acc, 16-step x chunk staging,
// __syncthreads per step, rep/cls epilogue.
__global__ __launch_bounds__(512) void lstm_fused(
    const float* __restrict__ x,      // [2048][128][64] f32
    const float* __restrict__ Wih,    // [512][64] f32
    const float* __restrict__ Whh,    // [512][128] f32
    const float* __restrict__ bih,    // [512] f32
    const float* __restrict__ bhh,    // [512] f32
    float* __restrict__ rep)          // [2048][128] f32 (d_ws)
{
    __shared__ __align__(16) __hip_bfloat16 hbuf[2][8][HPAD];          // 4352 B
    __shared__ __align__(16) __hip_bfloat16 xs[2][CHK][8][XPAD];       // 36864 B

    const int tid  = threadIdx.x;
    const int w    = tid >> 6;
    const int lane = tid & 63;
    const int ln   = lane & 15;
    const int qd   = lane >> 4;
    const int s0   = blockIdx.x * 8;
    const int khid = w * 16 + ln;
    const int arow = ln >> 1;          // A-side LDS row: seq of M-row ln
    // this lane's two directly-owned sequences (C rows 4qd..4qd+3 -> seqs)
    const int sq0  = 2 * qd;
    const int sq1  = 2 * qd + 1;

    // ---- weight B-fragments: f32 -> bf16 registers (reused all 128 steps) ----
    bfrag8 whh[4][4];
    bfrag8 wih[4][2];
    facc4  biasf[4];    // bias as persistent MFMA C-input
#pragma unroll
    for (int g = 0; g < 4; ++g) {
        const int col = g * HID + khid;
        const float b = bih[col] + bhh[col];
        biasf[g] = (facc4){b, b, b, b};
#pragma unroll
        for (int k0 = 0; k0 < 4; ++k0)
            whh[g][k0] = load_bf16_frag(Whh + col * HID + k0 * 32 + qd * 8);
#pragma unroll
        for (int k0 = 0; k0 < 2; ++k0)
            wih[g][k0] = load_bf16_frag(Wih + col * DIN + k0 * 32 + qd * 8);
    }

    // zero both h buffers (h(-1) = 0)
    {
        unsigned int* p = (unsigned int*)&hbuf[0][0][0];
        for (int i = tid; i < 2 * 8 * HPAD / 2; i += 512) p[i] = 0u;
    }

    // x staging: wave w stages sequence s0+w; lane covers 16 consecutive f32.
    const float* xsrc = x + (size_t)(s0 + w) * (LSEQ * DIN) + lane * 16;
    const int stt = lane >> 2;
    const int sdd = (lane & 3) * 16;

    {   // stage chunk 0
        float4 a0 = ((const float4*)xsrc)[0];
        float4 a1 = ((const float4*)xsrc)[1];
        float4 a2 = ((const float4*)xsrc)[2];
        float4 a3 = ((const float4*)xsrc)[3];
        bfrag8 o0, o1;
#pragma unroll
        for (int j = 0; j < 4; ++j) { o0[j] = f2bf(((float*)&a0)[j]); o0[4+j] = f2bf(((float*)&a1)[j]); }
#pragma unroll
        for (int j = 0; j < 4; ++j) { o1[j] = f2bf(((float*)&a2)[j]); o1[4+j] = f2bf(((float*)&a3)[j]); }
        *(bfrag8*)&xs[0][stt][w][sdd]     = o0;
        *(bfrag8*)&xs[0][stt][w][sdd + 8] = o1;
    }

    float cst[2]  = {0.f, 0.f};
    float hsum[2] = {0.f, 0.f};

    __syncthreads();

    // prologue: acc for t=0 = bias + x(0) @ Wih^T  (dup rows ln>>1)
    facc4 accA[4], accB[4];
    {
        bfrag8 x0 = *(const bfrag8*)(&xs[0][0][arow][qd * 8]);
        bfrag8 x1 = *(const bfrag8*)(&xs[0][0][arow][32 + qd * 8]);
#pragma unroll
        for (int g = 0; g < 4; ++g) {
            accA[g] = __builtin_amdgcn_mfma_f32_16x16x32_bf16(x0, wih[g][0], biasf[g], 0, 0, 0);
            accA[g] = __builtin_amdgcn_mfma_f32_16x16x32_bf16(x1, wih[g][1], accA[g], 0, 0, 0);
        }
    }

    int cur = 0;

#define STEP(ACCIN, ACCOUT, CT)                                                          \
    {                                                                                    \
        const int ct = (CT);                                                             \
        /* h A-frags, dup rows ln>>1 (post-barrier critical path) */                     \
        bfrag8 hf[4];                                                                    \
        _Pragma("unroll")                                                                \
        for (int k0 = 0; k0 < 4; ++k0)                                                   \
            hf[k0] = *(const bfrag8*)(&hbuf[cur][arow][k0 * 32 + qd * 8]);               \
        /* x A-frags for t+1 (stable chunk buffer; ct==15 -> next chunk's buffer) */     \
        const int nbuf = (ct < CHK - 1) ? buf : (buf ^ 1);                               \
        const int nct  = (ct + 1) & (CHK - 1);                                           \
        bfrag8 xf0 = *(const bfrag8*)(&xs[nbuf][nct][arow][qd * 8]);                     \
        bfrag8 xf1 = *(const bfrag8*)(&xs[nbuf][nct][arow][32 + qd * 8]);                \
        /* h-part MFMAs into carried acc (which already holds bias + x(t)) */            \
        _Pragma("unroll")                                                                \
        for (int g = 0; g < 4; ++g)                                                      \
            _Pragma("unroll")                                                            \
            for (int k0 = 0; k0 < 4; ++k0)                                               \
                ACCIN[g] = __builtin_amdgcn_mfma_f32_16x16x32_bf16(hf[k0], whh[g][k0], ACCIN[g], 0, 0, 0); \
        /* direct ownership: element 0 -> seq 2qd, element 2 -> seq 2qd+1 */             \
        float u0[4], u1[4];                                                              \
        _Pragma("unroll")                                                                \
        for (int g = 0; g < 4; ++g) { u0[g] = ACCIN[g][0]; u1[g] = ACCIN[g][2]; }        \
        /* next step's x-part: fills MFMA pipe during cell phase (C = biasf) */          \
        _Pragma("unroll")                                                                \
        for (int g = 0; g < 4; ++g) {                                                    \
            ACCOUT[g] = __builtin_amdgcn_mfma_f32_16x16x32_bf16(xf0, wih[g][0], biasf[g], 0, 0, 0); \
            ACCOUT[g] = __builtin_amdgcn_mfma_f32_16x16x32_bf16(xf1, wih[g][1], ACCOUT[g], 0, 0, 0); \
        }                                                                                \
        if (ct == 0 && more) {      /* issue next chunk's global loads */                \
            const float* p = xsrc + (chunk + 1) * (CHK * DIN);                           \
            l0 = ((const float4*)p)[0];                                                  \
            l1 = ((const float4*)p)[1];                                                  \
            l2 = ((const float4*)p)[2];                                                  \
            l3 = ((const float4*)p)[3];                                                  \
        }                                                                                \
        if (ct == 12 && more) {     /* convert + write next chunk to LDS */              \
            bfrag8 o0, o1;                                                               \
            _Pragma("unroll")                                                            \
            for (int j = 0; j < 4; ++j) { o0[j] = f2bf(((float*)&l0)[j]); o0[4+j] = f2bf(((float*)&l1)[j]); } \
            _Pragma("unroll")                                                            \
            for (int j = 0; j < 4; ++j) { o1[j] = f2bf(((float*)&l2)[j]); o1[4+j] = f2bf(((float*)&l3)[j]); } \
            *(bfrag8*)&xs[buf ^ 1][stt][w][sdd]     = o0;                                \
            *(bfrag8*)&xs[buf ^ 1][stt][w][sdd + 8] = o1;                                \
        }                                                                                \
        /* LSTM cell on this lane's 2 directly-owned (seq, hid) units */                 \
        short hb[2];                                                                     \
        _Pragma("unroll")                                                                \
        for (int j = 0; j < 2; ++j) {                                                    \
            float iv = fast_sigmoid(j ? u1[0] : u0[0]);                                  \
            float fv = fast_sigmoid(j ? u1[1] : u0[1]);                                  \
            float gv = fast_tanh(j ? u1[2] : u0[2]);                                     \
            float ov = fast_sigmoid(j ? u1[3] : u0[3]);                                  \
            float c  = fv * cst[j] + iv * gv;                                            \
            cst[j]   = c;                                                                \
            float hv = ov * fast_tanh(c);                                                \
            hsum[j] += hv;                                                               \
            hb[j]    = f2bf(hv);                                                         \
        }                                                                                \
        ((short*)&hbuf[cur ^ 1][sq0][0])[khid] = hb[0];                                  \
        ((short*)&hbuf[cur ^ 1][sq1][0])[khid] = hb[1];                                  \
        __syncthreads();                                                                 \
        cur ^= 1;                                                                        \
    }

    for (int chunk = 0; chunk < LSEQ / CHK; ++chunk) {
        const int buf = chunk & 1;
        const bool more = chunk < (LSEQ / CHK - 1);
        float4 l0, l1, l2, l3;
#pragma unroll 1
        for (int ct2 = 0; ct2 < CHK / 2; ++ct2) {
            STEP(accA, accB, 2 * ct2);
            STEP(accB, accA, 2 * ct2 + 1);
        }
    }
#undef STEP

    // rep[b][k] = sum_t h_t[b][k] — every lane writes its 2 owned seqs
    rep[(size_t)(s0 + sq0) * HID + khid] = hsum[0];
    rep[(size_t)(s0 + sq1) * HID + khid] = hsum[1];
}

// Epilogue: graph mean over C=32, classifier [10,128], log-softmax -> f32 out[64][10]
__global__ __launch_bounds__(128) void cls_kernel(
    const float* __restrict__ rep,    // [2048][128]
    const float* __restrict__ Wcls,   // [10][128]
    const float* __restrict__ bcls,   // [10]
    float* __restrict__ out)          // [64][10]
{
    __shared__ float m_s[HID];
    __shared__ float logits_s[NCLS];
    const int g = blockIdx.x;
    const int h = threadIdx.x;

    float s = 0.f;
#pragma unroll 4
    for (int c = 0; c < 32; ++c)
        s += rep[((size_t)g * 32 + c) * HID + h];
    m_s[h] = s * (1.0f / 32.0f);
    __syncthreads();

    if (h < NCLS) {
        float acc = bcls[h];
        for (int k = 0; k < HID; ++k)
            acc += m_s[k] * Wcls[h * HID + k];
        logits_s[h] = acc;
    }
    __syncthreads();

    if (h < NCLS) {
        float mx = logits_s[0];
#pragma unroll
        for (int j = 1; j < NCLS; ++j) mx = fmaxf(mx, logits_s[j]);
        float se = 0.f;
#pragma unroll
        for (int j = 0; j < NCLS; ++j)
            se += __builtin_amdgcn_exp2f((logits_s[j] - mx) * 1.4426950408889634f);
        float lse = mx + 0.6931471805599453f * __builtin_amdgcn_logf(se);
        out[g * NCLS + h] = logits_s[h] - lse;
    }
}

extern "C" void kernel_launch(void* const* d_in, const int* in_sizes, int n_in,
                              void* d_out, int out_size, void* d_ws, size_t ws_size,
                              hipStream_t stream) {
    const float* x    = (const float*)d_in[0];
    const float* Wih  = (const float*)d_in[1];
    const float* Whh  = (const float*)d_in[2];
    const float* bih  = (const float*)d_in[3];
    const float* bhh  = (const float*)d_in[4];
    const float* Wcls = (const float*)d_in[5];
    const float* bcls = (const float*)d_in[6];

    float* rep = (float*)d_ws;   // 2048*128 fp32 = 1 MB scratch

    lstm_fused<<<NSEQ / 8, 512, 0, stream>>>(x, Wih, Whh, bih, bhh, rep);
    cls_kernel<<<64, 128, 0, stream>>>(rep, Wcls, bcls, (float*)d_out);
}

// Round 8
// 190.892 us; speedup vs baseline: 1.3717x; 1.0011x over previous
//
#include <hip/hip_runtime.h>
#include <hip/hip_bf16.h>

// Problem constants: G=64, C=32, L=128, D=64, H=128, NCLS=10
#define NSEQ 2048   // G*C
#define LSEQ 128
#define DIN  64
#define HID  128
#define NCLS 10
#define XPAD 72     // padded x row (shorts)
#define HPAD 136    // padded h row (shorts)
#define CHK  16     // timesteps staged per chunk

typedef __attribute__((ext_vector_type(8))) short bfrag8;   // 8 bf16 (MFMA A/B frag)
typedef __attribute__((ext_vector_type(4))) float facc4;    // MFMA C/D frag

__device__ __forceinline__ short f2bf(float f) {
    union { __hip_bfloat16 b; short s; } u;
    u.b = __float2bfloat16(f);   // RNE
    return u.s;
}

__device__ __forceinline__ bfrag8 load_bf16_frag(const float* __restrict__ p) {
    bfrag8 r;
#pragma unroll
    for (int j = 0; j < 8; ++j) r[j] = f2bf(p[j]);
    return r;
}

__device__ __forceinline__ float fast_sigmoid(float x) {
    float e = __builtin_amdgcn_exp2f(-1.4426950408889634f * x);
    return __builtin_amdgcn_rcpf(1.0f + e);
}
__device__ __forceinline__ float fast_tanh(float x) {
    float e = __builtin_amdgcn_exp2f(2.8853900817779268f * x);
    return 1.0f - 2.0f * __builtin_amdgcn_rcpf(1.0f + e);
}

// One block = 8 sequences, 8 waves, 2x ROW-DUP map (R7 winner):
// MFMA M-row r carries seq r>>1 (A-frags read LDS row ln>>1); lane (ln,qd)'s
// C-frag directly holds gates for seqs 2qd (elem 0) / 2qd+1 (elem 2) at col
// khid — no cross-lane redistribute.
// NEW (R8): WAVE-STAGGERED STEP ORDER. Waves w<4 run h-first (R7 order);
// waves w>=4 — which share SIMDs with waves 0-3 — run x-first: post-barrier
// they immediately issue the 8 x-part MFMAs for t+1 (no dependence on this
// step's h), feeding the SIMD's matrix pipe while the co-resident wave does
// its hf LDS reads, and running their cell while the other's h-MFMAs drain.
// Recurrence, numerics, and barrier counts are identical in both paths.
__global__ __launch_bounds__(512) void lstm_fused(
    const float* __restrict__ x,      // [2048][128][64] f32
    const float* __restrict__ Wih,    // [512][64] f32
    const float* __restrict__ Whh,    // [512][128] f32
    const float* __restrict__ bih,    // [512] f32
    const float* __restrict__ bhh,    // [512] f32
    float* __restrict__ rep)          // [2048][128] f32 (d_ws)
{
    __shared__ __align__(16) __hip_bfloat16 hbuf[2][8][HPAD];          // 4352 B
    __shared__ __align__(16) __hip_bfloat16 xs[2][CHK][8][XPAD];       // 36864 B

    const int tid  = threadIdx.x;
    const int w    = tid >> 6;
    const int lane = tid & 63;
    const int ln   = lane & 15;
    const int qd   = lane >> 4;
    const int s0   = blockIdx.x * 8;
    const int khid = w * 16 + ln;
    const int arow = ln >> 1;          // A-side LDS row: seq of M-row ln
    const int sq0  = 2 * qd;
    const int sq1  = 2 * qd + 1;

    // ---- weight B-fragments: f32 -> bf16 registers (reused all 128 steps) ----
    bfrag8 whh[4][4];
    bfrag8 wih[4][2];
    facc4  biasf[4];    // bias as persistent MFMA C-input
#pragma unroll
    for (int g = 0; g < 4; ++g) {
        const int col = g * HID + khid;
        const float b = bih[col] + bhh[col];
        biasf[g] = (facc4){b, b, b, b};
#pragma unroll
        for (int k0 = 0; k0 < 4; ++k0)
            whh[g][k0] = load_bf16_frag(Whh + col * HID + k0 * 32 + qd * 8);
#pragma unroll
        for (int k0 = 0; k0 < 2; ++k0)
            wih[g][k0] = load_bf16_frag(Wih + col * DIN + k0 * 32 + qd * 8);
    }

    // zero both h buffers (h(-1) = 0)
    {
        unsigned int* p = (unsigned int*)&hbuf[0][0][0];
        for (int i = tid; i < 2 * 8 * HPAD / 2; i += 512) p[i] = 0u;
    }

    // x staging: wave w stages sequence s0+w; lane covers 16 consecutive f32.
    const float* xsrc = x + (size_t)(s0 + w) * (LSEQ * DIN) + lane * 16;
    const int stt = lane >> 2;
    const int sdd = (lane & 3) * 16;

    {   // stage chunk 0
        float4 a0 = ((const float4*)xsrc)[0];
        float4 a1 = ((const float4*)xsrc)[1];
        float4 a2 = ((const float4*)xsrc)[2];
        float4 a3 = ((const float4*)xsrc)[3];
        bfrag8 o0, o1;
#pragma unroll
        for (int j = 0; j < 4; ++j) { o0[j] = f2bf(((float*)&a0)[j]); o0[4+j] = f2bf(((float*)&a1)[j]); }
#pragma unroll
        for (int j = 0; j < 4; ++j) { o1[j] = f2bf(((float*)&a2)[j]); o1[4+j] = f2bf(((float*)&a3)[j]); }
        *(bfrag8*)&xs[0][stt][w][sdd]     = o0;
        *(bfrag8*)&xs[0][stt][w][sdd + 8] = o1;
    }

    float cst[2]  = {0.f, 0.f};
    float hsum[2] = {0.f, 0.f};

    __syncthreads();

    // prologue: acc for t=0 = bias + x(0) @ Wih^T  (dup rows ln>>1)
    facc4 accA[4], accB[4];
    {
        bfrag8 x0 = *(const bfrag8*)(&xs[0][0][arow][qd * 8]);
        bfrag8 x1 = *(const bfrag8*)(&xs[0][0][arow][32 + qd * 8]);
#pragma unroll
        for (int g = 0; g < 4; ++g) {
            accA[g] = __builtin_amdgcn_mfma_f32_16x16x32_bf16(x0, wih[g][0], biasf[g], 0, 0, 0);
            accA[g] = __builtin_amdgcn_mfma_f32_16x16x32_bf16(x1, wih[g][1], accA[g], 0, 0, 0);
        }
    }

    int cur = 0;

// XF=0: h-first (R7 order). XF=1: x-part for t+1 issued first (post-barrier).
#define STEP(ACCIN, ACCOUT, CT, XF)                                                      \
    {                                                                                    \
        const int ct = (CT);                                                             \
        const int nbuf = (ct < CHK - 1) ? buf : (buf ^ 1);                               \
        const int nct  = (ct + 1) & (CHK - 1);                                           \
        bfrag8 hf[4];                                                                    \
        bfrag8 xf0, xf1;                                                                 \
        if (XF) {                                                                        \
            /* x A-frags + x-MFMAs FIRST: independent of this step's h */                \
            xf0 = *(const bfrag8*)(&xs[nbuf][nct][arow][qd * 8]);                        \
            xf1 = *(const bfrag8*)(&xs[nbuf][nct][arow][32 + qd * 8]);                   \
            _Pragma("unroll")                                                            \
            for (int g = 0; g < 4; ++g) {                                                \
                ACCOUT[g] = __builtin_amdgcn_mfma_f32_16x16x32_bf16(xf0, wih[g][0], biasf[g], 0, 0, 0); \
                ACCOUT[g] = __builtin_amdgcn_mfma_f32_16x16x32_bf16(xf1, wih[g][1], ACCOUT[g], 0, 0, 0); \
            }                                                                            \
            _Pragma("unroll")                                                            \
            for (int k0 = 0; k0 < 4; ++k0)                                               \
                hf[k0] = *(const bfrag8*)(&hbuf[cur][arow][k0 * 32 + qd * 8]);           \
        } else {                                                                         \
            _Pragma("unroll")                                                            \
            for (int k0 = 0; k0 < 4; ++k0)                                               \
                hf[k0] = *(const bfrag8*)(&hbuf[cur][arow][k0 * 32 + qd * 8]);           \
            xf0 = *(const bfrag8*)(&xs[nbuf][nct][arow][qd * 8]);                        \
            xf1 = *(const bfrag8*)(&xs[nbuf][nct][arow][32 + qd * 8]);                   \
        }                                                                                \
        /* h-part MFMAs into carried acc (which already holds bias + x(t)) */            \
        _Pragma("unroll")                                                                \
        for (int g = 0; g < 4; ++g)                                                      \
            _Pragma("unroll")                                                            \
            for (int k0 = 0; k0 < 4; ++k0)                                               \
                ACCIN[g] = __builtin_amdgcn_mfma_f32_16x16x32_bf16(hf[k0], whh[g][k0], ACCIN[g], 0, 0, 0); \
        /* direct ownership: element 0 -> seq 2qd, element 2 -> seq 2qd+1 */             \
        float u0[4], u1[4];                                                              \
        _Pragma("unroll")                                                                \
        for (int g = 0; g < 4; ++g) { u0[g] = ACCIN[g][0]; u1[g] = ACCIN[g][2]; }        \
        if (!XF) {                                                                       \
            /* next step's x-part: fills MFMA pipe during cell phase */                  \
            _Pragma("unroll")                                                            \
            for (int g = 0; g < 4; ++g) {                                                \
                ACCOUT[g] = __builtin_amdgcn_mfma_f32_16x16x32_bf16(xf0, wih[g][0], biasf[g], 0, 0, 0); \
                ACCOUT[g] = __builtin_amdgcn_mfma_f32_16x16x32_bf16(xf1, wih[g][1], ACCOUT[g], 0, 0, 0); \
            }                                                                            \
        }                                                                                \
        if (ct == 0 && more) {      /* issue next chunk's global loads */                \
            const float* p = xsrc + (chunk + 1) * (CHK * DIN);                           \
            l0 = ((const float4*)p)[0];                                                  \
            l1 = ((const float4*)p)[1];                                                  \
            l2 = ((const float4*)p)[2];                                                  \
            l3 = ((const float4*)p)[3];                                                  \
        }                                                                                \
        if (ct == 12 && more) {     /* convert + write next chunk to LDS */              \
            bfrag8 o0, o1;                                                               \
            _Pragma("unroll")                                                            \
            for (int j = 0; j < 4; ++j) { o0[j] = f2bf(((float*)&l0)[j]); o0[4+j] = f2bf(((float*)&l1)[j]); } \
            _Pragma("unroll")                                                            \
            for (int j = 0; j < 4; ++j) { o1[j] = f2bf(((float*)&l2)[j]); o1[4+j] = f2bf(((float*)&l3)[j]); } \
            *(bfrag8*)&xs[buf ^ 1][stt][w][sdd]     = o0;                                \
            *(bfrag8*)&xs[buf ^ 1][stt][w][sdd + 8] = o1;                                \
        }                                                                                \
        /* LSTM cell on this lane's 2 directly-owned (seq, hid) units */                 \
        short hb[2];                                                                     \
        _Pragma("unroll")                                                                \
        for (int j = 0; j < 2; ++j) {                                                    \
            float iv = fast_sigmoid(j ? u1[0] : u0[0]);                                  \
            float fv = fast_sigmoid(j ? u1[1] : u0[1]);                                  \
            float gv = fast_tanh(j ? u1[2] : u0[2]);                                     \
            float ov = fast_sigmoid(j ? u1[3] : u0[3]);                                  \
            float c  = fv * cst[j] + iv * gv;                                            \
            cst[j]   = c;                                                                \
            float hv = ov * fast_tanh(c);                                                \
            hsum[j] += hv;                                                               \
            hb[j]    = f2bf(hv);                                                         \
        }                                                                                \
        ((short*)&hbuf[cur ^ 1][sq0][0])[khid] = hb[0];                                  \
        ((short*)&hbuf[cur ^ 1][sq1][0])[khid] = hb[1];                                  \
        __syncthreads();                                                                 \
        cur ^= 1;                                                                        \
    }

    if (w < 4) {
        for (int chunk = 0; chunk < LSEQ / CHK; ++chunk) {
            const int buf = chunk & 1;
            const bool more = chunk < (LSEQ / CHK - 1);
            float4 l0, l1, l2, l3;
#pragma unroll 1
            for (int ct2 = 0; ct2 < CHK / 2; ++ct2) {
                STEP(accA, accB, 2 * ct2, 0);
                STEP(accB, accA, 2 * ct2 + 1, 0);
            }
        }
    } else {
        for (int chunk = 0; chunk < LSEQ / CHK; ++chunk) {
            const int buf = chunk & 1;
            const bool more = chunk < (LSEQ / CHK - 1);
            float4 l0, l1, l2, l3;
#pragma unroll 1
            for (int ct2 = 0; ct2 < CHK / 2; ++ct2) {
                STEP(accA, accB, 2 * ct2, 1);
                STEP(accB, accA, 2 * ct2 + 1, 1);
            }
        }
    }
#undef STEP

    // rep[b][k] = sum_t h_t[b][k] — every lane writes its 2 owned seqs
    rep[(size_t)(s0 + sq0) * HID + khid] = hsum[0];
    rep[(size_t)(s0 + sq1) * HID + khid] = hsum[1];
}

// Epilogue: graph mean over C=32, classifier [10,128], log-softmax -> f32 out[64][10]
__global__ __launch_bounds__(128) void cls_kernel(
    const float* __restrict__ rep,    // [2048][128]
    const float* __restrict__ Wcls,   // [10][128]
    const float* __restrict__ bcls,   // [10]
    float* __restrict__ out)          // [64][10]
{
    __shared__ float m_s[HID];
    __shared__ float logits_s[NCLS];
    const int g = blockIdx.x;
    const int h = threadIdx.x;

    float s = 0.f;
#pragma unroll 4
    for (int c = 0; c < 32; ++c)
        s += rep[((size_t)g * 32 + c) * HID + h];
    m_s[h] = s * (1.0f / 32.0f);
    __syncthreads();

    if (h < NCLS) {
        float acc = bcls[h];
        for (int k = 0; k < HID; ++k)
            acc += m_s[k] * Wcls[h * HID + k];
        logits_s[h] = acc;
    }
    __syncthreads();

    if (h < NCLS) {
        float mx = logits_s[0];
#pragma unroll
        for (int j = 1; j < NCLS; ++j) mx = fmaxf(mx, logits_s[j]);
        float se = 0.f;
#pragma unroll
        for (int j = 0; j < NCLS; ++j)
            se += __builtin_amdgcn_exp2f((logits_s[j] - mx) * 1.4426950408889634f);
        float lse = mx + 0.6931471805599453f * __builtin_amdgcn_logf(se);
        out[g * NCLS + h] = logits_s[h] - lse;
    }
}

extern "C" void kernel_launch(void* const* d_in, const int* in_sizes, int n_in,
                              void* d_out, int out_size, void* d_ws, size_t ws_size,
                              hipStream_t stream) {
    const float* x    = (const float*)d_in[0];
    const float* Wih  = (const float*)d_in[1];
    const float* Whh  = (const float*)d_in[2];
    const float* bih  = (const float*)d_in[3];
    const float* bhh  = (const float*)d_in[4];
    const float* Wcls = (const float*)d_in[5];
    const float* bcls = (const float*)d_in[6];

    float* rep = (float*)d_ws;   // 2048*128 fp32 = 1 MB scratch

    lstm_fused<<<NSEQ / 8, 512, 0, stream>>>(x, Wih, Whh, bih, bhh, rep);
    cls_kernel<<<64, 128, 0, stream>>>(rep, Wcls, bcls, (float*)d_out);
}

// Round 9
// 190.017 us; speedup vs baseline: 1.3780x; 1.0046x over previous
//
#include <hip/hip_runtime.h>
#include <hip/hip_bf16.h>

// Problem constants: G=64, C=32, L=128, D=64, H=128, NCLS=10
#define NSEQ 2048   // G*C
#define LSEQ 128
#define DIN  64
#define HID  128
#define NCLS 10
#define XPAD 72     // padded x row (shorts)
#define HPAD 136    // padded h row (shorts)
#define CHK  16     // timesteps staged per chunk

typedef __attribute__((ext_vector_type(8))) short bfrag8;   // 8 bf16 (MFMA A/B frag)
typedef __attribute__((ext_vector_type(4))) float facc4;    // MFMA C/D frag

__device__ __forceinline__ short f2bf(float f) {
    union { __hip_bfloat16 b; short s; } u;
    u.b = __float2bfloat16(f);   // RNE
    return u.s;
}

__device__ __forceinline__ bfrag8 load_bf16_frag(const float* __restrict__ p) {
    bfrag8 r;
#pragma unroll
    for (int j = 0; j < 8; ++j) r[j] = f2bf(p[j]);
    return r;
}

__device__ __forceinline__ float fast_sigmoid(float x) {
    float e = __builtin_amdgcn_exp2f(-1.4426950408889634f * x);
    return __builtin_amdgcn_rcpf(1.0f + e);
}
__device__ __forceinline__ float fast_tanh(float x) {
    float e = __builtin_amdgcn_exp2f(2.8853900817779268f * x);
    return 1.0f - 2.0f * __builtin_amdgcn_rcpf(1.0f + e);
}

// Raw block barrier: LDS-visibility only (s_waitcnt lgkmcnt(0)); the chunk
// staging loads issued at ct==0 stay in flight across barriers instead of
// being force-drained by __syncthreads' vmcnt(0) at that step's barrier
// (~900 cy HBM latency x 8 chunk boundaries). R2 validated correctness of
// this barrier on this exact macro structure.
__device__ __forceinline__ void block_barrier() {
    asm volatile("s_waitcnt lgkmcnt(0)" ::: "memory");
    __builtin_amdgcn_s_barrier();
    asm volatile("" ::: "memory");
}

// One block = 8 sequences, 8 waves, 2x ROW-DUP map (R7 winner):
// MFMA M-row r carries seq r>>1 (A-frags read LDS row ln>>1); lane (ln,qd)'s
// C-frag directly holds gates for seqs 2qd (elem 0) / 2qd+1 (elem 2) at col
// khid — no cross-lane redistribute.
// R9: (1) chunk loop FULLY unrolled (ct/nbuf/nct/staging predicates all
// compile-time -> branch/SALU ops leave the serial region); (2) lgkm-only
// barrier; (3) setprio(1) around the MFMA cluster (T5: favors the wave
// entering MFMA while its co-resident wave is in the trans-heavy cell).
__global__ __launch_bounds__(512) void lstm_fused(
    const float* __restrict__ x,      // [2048][128][64] f32
    const float* __restrict__ Wih,    // [512][64] f32
    const float* __restrict__ Whh,    // [512][128] f32
    const float* __restrict__ bih,    // [512] f32
    const float* __restrict__ bhh,    // [512] f32
    float* __restrict__ rep)          // [2048][128] f32 (d_ws)
{
    __shared__ __align__(16) __hip_bfloat16 hbuf[2][8][HPAD];          // 4352 B
    __shared__ __align__(16) __hip_bfloat16 xs[2][CHK][8][XPAD];       // 36864 B

    const int tid  = threadIdx.x;
    const int w    = tid >> 6;
    const int lane = tid & 63;
    const int ln   = lane & 15;
    const int qd   = lane >> 4;
    const int s0   = blockIdx.x * 8;
    const int khid = w * 16 + ln;
    const int arow = ln >> 1;          // A-side LDS row: seq of M-row ln
    const int sq0  = 2 * qd;
    const int sq1  = 2 * qd + 1;

    // ---- weight B-fragments: f32 -> bf16 registers (reused all 128 steps) ----
    bfrag8 whh[4][4];
    bfrag8 wih[4][2];
    facc4  biasf[4];    // bias as persistent MFMA C-input
#pragma unroll
    for (int g = 0; g < 4; ++g) {
        const int col = g * HID + khid;
        const float b = bih[col] + bhh[col];
        biasf[g] = (facc4){b, b, b, b};
#pragma unroll
        for (int k0 = 0; k0 < 4; ++k0)
            whh[g][k0] = load_bf16_frag(Whh + col * HID + k0 * 32 + qd * 8);
#pragma unroll
        for (int k0 = 0; k0 < 2; ++k0)
            wih[g][k0] = load_bf16_frag(Wih + col * DIN + k0 * 32 + qd * 8);
    }

    // zero both h buffers (h(-1) = 0)
    {
        unsigned int* p = (unsigned int*)&hbuf[0][0][0];
        for (int i = tid; i < 2 * 8 * HPAD / 2; i += 512) p[i] = 0u;
    }

    // x staging: wave w stages sequence s0+w; lane covers 16 consecutive f32.
    const float* xsrc = x + (size_t)(s0 + w) * (LSEQ * DIN) + lane * 16;
    const int stt = lane >> 2;
    const int sdd = (lane & 3) * 16;

    {   // stage chunk 0
        float4 a0 = ((const float4*)xsrc)[0];
        float4 a1 = ((const float4*)xsrc)[1];
        float4 a2 = ((const float4*)xsrc)[2];
        float4 a3 = ((const float4*)xsrc)[3];
        bfrag8 o0, o1;
#pragma unroll
        for (int j = 0; j < 4; ++j) { o0[j] = f2bf(((float*)&a0)[j]); o0[4+j] = f2bf(((float*)&a1)[j]); }
#pragma unroll
        for (int j = 0; j < 4; ++j) { o1[j] = f2bf(((float*)&a2)[j]); o1[4+j] = f2bf(((float*)&a3)[j]); }
        *(bfrag8*)&xs[0][stt][w][sdd]     = o0;
        *(bfrag8*)&xs[0][stt][w][sdd + 8] = o1;
    }

    float cst[2]  = {0.f, 0.f};
    float hsum[2] = {0.f, 0.f};

    block_barrier();

    // prologue: acc for t=0 = bias + x(0) @ Wih^T  (dup rows ln>>1)
    facc4 accA[4], accB[4];
    {
        bfrag8 x0 = *(const bfrag8*)(&xs[0][0][arow][qd * 8]);
        bfrag8 x1 = *(const bfrag8*)(&xs[0][0][arow][32 + qd * 8]);
#pragma unroll
        for (int g = 0; g < 4; ++g) {
            accA[g] = __builtin_amdgcn_mfma_f32_16x16x32_bf16(x0, wih[g][0], biasf[g], 0, 0, 0);
            accA[g] = __builtin_amdgcn_mfma_f32_16x16x32_bf16(x1, wih[g][1], accA[g], 0, 0, 0);
        }
    }

    int cur = 0;

#define STEP(ACCIN, ACCOUT, CT)                                                          \
    {                                                                                    \
        const int ct = (CT);                                                             \
        /* h A-frags, dup rows ln>>1 (post-barrier critical path) */                     \
        bfrag8 hf[4];                                                                    \
        _Pragma("unroll")                                                                \
        for (int k0 = 0; k0 < 4; ++k0)                                                   \
            hf[k0] = *(const bfrag8*)(&hbuf[cur][arow][k0 * 32 + qd * 8]);               \
        /* x A-frags for t+1 (stable chunk buffer; ct==15 -> next chunk's buffer) */     \
        const int nbuf = (ct < CHK - 1) ? buf : (buf ^ 1);                               \
        const int nct  = (ct + 1) & (CHK - 1);                                           \
        bfrag8 xf0 = *(const bfrag8*)(&xs[nbuf][nct][arow][qd * 8]);                     \
        bfrag8 xf1 = *(const bfrag8*)(&xs[nbuf][nct][arow][32 + qd * 8]);                \
        /* h-part MFMAs into carried acc (which already holds bias + x(t)) */            \
        __builtin_amdgcn_s_setprio(1);                                                   \
        _Pragma("unroll")                                                                \
        for (int g = 0; g < 4; ++g)                                                      \
            _Pragma("unroll")                                                            \
            for (int k0 = 0; k0 < 4; ++k0)                                               \
                ACCIN[g] = __builtin_amdgcn_mfma_f32_16x16x32_bf16(hf[k0], whh[g][k0], ACCIN[g], 0, 0, 0); \
        /* next step's x-part: fills MFMA pipe during cell phase (C = biasf) */          \
        _Pragma("unroll")                                                                \
        for (int g = 0; g < 4; ++g) {                                                    \
            ACCOUT[g] = __builtin_amdgcn_mfma_f32_16x16x32_bf16(xf0, wih[g][0], biasf[g], 0, 0, 0); \
            ACCOUT[g] = __builtin_amdgcn_mfma_f32_16x16x32_bf16(xf1, wih[g][1], ACCOUT[g], 0, 0, 0); \
        }                                                                                \
        __builtin_amdgcn_s_setprio(0);                                                   \
        /* direct ownership: element 0 -> seq 2qd, element 2 -> seq 2qd+1 */             \
        float u0[4], u1[4];                                                              \
        _Pragma("unroll")                                                                \
        for (int g = 0; g < 4; ++g) { u0[g] = ACCIN[g][0]; u1[g] = ACCIN[g][2]; }        \
        if (ct == 0 && more) {      /* issue next chunk's global loads */                \
            const float* p = xsrc + (chunk + 1) * (CHK * DIN);                           \
            l0 = ((const float4*)p)[0];                                                  \
            l1 = ((const float4*)p)[1];                                                  \
            l2 = ((const float4*)p)[2];                                                  \
            l3 = ((const float4*)p)[3];                                                  \
        }                                                                                \
        if (ct == 12 && more) {     /* convert + write next chunk to LDS */              \
            bfrag8 o0, o1;                                                               \
            _Pragma("unroll")                                                            \
            for (int j = 0; j < 4; ++j) { o0[j] = f2bf(((float*)&l0)[j]); o0[4+j] = f2bf(((float*)&l1)[j]); } \
            _Pragma("unroll")                                                            \
            for (int j = 0; j < 4; ++j) { o1[j] = f2bf(((float*)&l2)[j]); o1[4+j] = f2bf(((float*)&l3)[j]); } \
            *(bfrag8*)&xs[buf ^ 1][stt][w][sdd]     = o0;                                \
            *(bfrag8*)&xs[buf ^ 1][stt][w][sdd + 8] = o1;                                \
        }                                                                                \
        /* LSTM cell on this lane's 2 directly-owned (seq, hid) units */                 \
        short hb[2];                                                                     \
        _Pragma("unroll")                                                                \
        for (int j = 0; j < 2; ++j) {                                                    \
            float iv = fast_sigmoid(j ? u1[0] : u0[0]);                                  \
            float fv = fast_sigmoid(j ? u1[1] : u0[1]);                                  \
            float gv = fast_tanh(j ? u1[2] : u0[2]);                                     \
            float ov = fast_sigmoid(j ? u1[3] : u0[3]);                                  \
            float c  = fv * cst[j] + iv * gv;                                            \
            cst[j]   = c;                                                                \
            float hv = ov * fast_tanh(c);                                                \
            hsum[j] += hv;                                                               \
            hb[j]    = f2bf(hv);                                                         \
        }                                                                                \
        ((short*)&hbuf[cur ^ 1][sq0][0])[khid] = hb[0];                                  \
        ((short*)&hbuf[cur ^ 1][sq1][0])[khid] = hb[1];                                  \
        block_barrier();                                                                 \
        cur ^= 1;                                                                        \
    }

#pragma unroll 1
    for (int chunk = 0; chunk < LSEQ / CHK; ++chunk) {
        const int buf = chunk & 1;
        const bool more = chunk < (LSEQ / CHK - 1);
        float4 l0, l1, l2, l3;
#pragma unroll
        for (int ct2 = 0; ct2 < CHK / 2; ++ct2) {
            STEP(accA, accB, 2 * ct2);
            STEP(accB, accA, 2 * ct2 + 1);
        }
    }
#undef STEP

    // rep[b][k] = sum_t h_t[b][k] — every lane writes its 2 owned seqs
    rep[(size_t)(s0 + sq0) * HID + khid] = hsum[0];
    rep[(size_t)(s0 + sq1) * HID + khid] = hsum[1];
}

// Epilogue: graph mean over C=32, classifier [10,128], log-softmax -> f32 out[64][10]
__global__ __launch_bounds__(128) void cls_kernel(
    const float* __restrict__ rep,    // [2048][128]
    const float* __restrict__ Wcls,   // [10][128]
    const float* __restrict__ bcls,   // [10]
    float* __restrict__ out)          // [64][10]
{
    __shared__ float m_s[HID];
    __shared__ float logits_s[NCLS];
    const int g = blockIdx.x;
    const int h = threadIdx.x;

    float s = 0.f;
#pragma unroll 4
    for (int c = 0; c < 32; ++c)
        s += rep[((size_t)g * 32 + c) * HID + h];
    m_s[h] = s * (1.0f / 32.0f);
    __syncthreads();

    if (h < NCLS) {
        float acc = bcls[h];
        for (int k = 0; k < HID; ++k)
            acc += m_s[k] * Wcls[h * HID + k];
        logits_s[h] = acc;
    }
    __syncthreads();

    if (h < NCLS) {
        float mx = logits_s[0];
#pragma unroll
        for (int j = 1; j < NCLS; ++j) mx = fmaxf(mx, logits_s[j]);
        float se = 0.f;
#pragma unroll
        for (int j = 0; j < NCLS; ++j)
            se += __builtin_amdgcn_exp2f((logits_s[j] - mx) * 1.4426950408889634f);
        float lse = mx + 0.6931471805599453f * __builtin_amdgcn_logf(se);
        out[g * NCLS + h] = logits_s[h] - lse;
    }
}

extern "C" void kernel_launch(void* const* d_in, const int* in_sizes, int n_in,
                              void* d_out, int out_size, void* d_ws, size_t ws_size,
                              hipStream_t stream) {
    const float* x    = (const float*)d_in[0];
    const float* Wih  = (const float*)d_in[1];
    const float* Whh  = (const float*)d_in[2];
    const float* bih  = (const float*)d_in[3];
    const float* bhh  = (const float*)d_in[4];
    const float* Wcls = (const float*)d_in[5];
    const float* bcls = (const float*)d_in[6];

    float* rep = (float*)d_ws;   // 2048*128 fp32 = 1 MB scratch

    lstm_fused<<<NSEQ / 8, 512, 0, stream>>>(x, Wih, Whh, bih, bhh, rep);
    cls_kernel<<<64, 128, 0, stream>>>(rep, Wcls, bcls, (float*)d_out);
}